// Round 12
// baseline (515.619 us; speedup 1.0000x reference)
//
#include <hip/hip_runtime.h>
#include <math.h>

#define S_LEN  2048
#define D_DIM  1024
#define NHEAD  16
#define HDK    64
#define NBATCH 4
#define NXELEM (8388608)   // B*S*D
#define NWELEM (1048576)   // D*D

typedef __attribute__((ext_vector_type(8))) short bf16x8;   // 8 bf16 (4 VGPRs)
typedef __attribute__((ext_vector_type(4))) float f32x4;    // MFMA C/D

#define MFMA16(a, b, c) __builtin_amdgcn_mfma_f32_16x16x32_bf16((a), (b), (c), 0, 0, 0)

// MFMA 16x16x32 layouts (guide §3, m89/m91-verified):
//   A-frag: lane holds row (l&15), k = (l>>4)*8 + i (8 contiguous bf16)
//   B-frag: lane holds col (l&15), k = (l>>4)*8 + i
//   C/D:    lane holds col (l&15), row = (l>>4)*4 + reg

__device__ __forceinline__ unsigned short f2bf(float f) {   // RNE float->bf16
    unsigned u = __float_as_uint(f);
    u += 0x7fffu + ((u >> 16) & 1u);
    return (unsigned short)(u >> 16);
}

// Barrier that does NOT drain vmcnt: global->reg prefetches stay in flight.
__device__ __forceinline__ void barrier_keep_vmem() {
    asm volatile("s_waitcnt lgkmcnt(0)" ::: "memory");
    __builtin_amdgcn_s_barrier();
    __builtin_amdgcn_sched_barrier(0);
}

// ---------------------------------------------------------------------------
// Single fused fp32->bf16 convert for x + 4 weights (dst regions contiguous).
// Grid: 4096 (x) + 4*512 (weights) = 6144 blocks.
// ---------------------------------------------------------------------------
__global__ __launch_bounds__(256)
void convert_all_kernel(const float* __restrict__ x,  const float* __restrict__ wq,
                        const float* __restrict__ wk, const float* __restrict__ wv,
                        const float* __restrict__ wo, unsigned short* __restrict__ dstbase)
{
    int bid = blockIdx.x;
    const float* src;
    unsigned short* dst;
    int lb;
    if (bid < 4096) { src = x; dst = dstbase; lb = bid; }
    else {
        int r = (bid - 4096) >> 9;
        lb = (bid - 4096) & 511;
        src = (r == 0) ? wq : (r == 1) ? wk : (r == 2) ? wv : wo;
        dst = dstbase + (size_t)NXELEM + (size_t)r * NWELEM;
    }
    int i = (lb * 256 + threadIdx.x) * 8;
    float4 f0 = *(const float4*)&src[i];
    float4 f1 = *(const float4*)&src[i + 4];
    uint4 o;
    o.x = f2bf(f0.x) | ((unsigned)f2bf(f0.y) << 16);
    o.y = f2bf(f0.z) | ((unsigned)f2bf(f0.w) << 16);
    o.z = f2bf(f1.x) | ((unsigned)f2bf(f1.y) << 16);
    o.w = f2bf(f1.z) | ((unsigned)f2bf(f1.w) << 16);
    *(uint4*)&dst[i] = o;
}

// ---------------------------------------------------------------------------
// Fused Q/K/V projection, bf16 MFMA, BK=64 (16 iters, 32 MFMA/barrier).
// 128x128 tile, 4 waves.  Grid (24,64); blockIdx.x>>3 selects W.
// Q: RoPE * 1/8 -> (B,H,S,DK).  K: RoPE -> (B,H,S,DK).  V: (B,H,DK,S).
// Staging: thread t loads 64B contiguous (row t>>1, col (t&1)*32..+31).
// ---------------------------------------------------------------------------
__global__ __launch_bounds__(256)
void proj_qkv_kernel(const unsigned short* __restrict__ Xb,
                     const unsigned short* __restrict__ Wqb,
                     const unsigned short* __restrict__ Wkb,
                     const unsigned short* __restrict__ Wvb,
                     const int* __restrict__ pos,
                     unsigned short* __restrict__ Qb,
                     unsigned short* __restrict__ Kb,
                     unsigned short* __restrict__ Vtb)
{
    __shared__ short As[128][72];   // [m][k] bf16, BK=64 + pad8 (144B rows, 16B-aligned)
    __shared__ short Bs[128][72];   // [n][k]

    const int t  = threadIdx.x;
    const int l  = t & 63;
    const int w  = t >> 6;
    const int wr = w >> 1, wc = w & 1;
    const int lm = l & 15;
    const int lk = (l >> 4) * 8;

    const int nb   = blockIdx.x;
    const int wsel = nb >> 3;
    const int n0   = (nb & 7) * 128;
    const int m0   = blockIdx.y * 128;
    const unsigned short* W = (wsel == 0) ? Wqb : (wsel == 1) ? Wkb : Wvb;

    const int sr = t >> 1;          // 0..127
    const int sc = (t & 1) * 32;    // 0 or 32

    f32x4 acc[4][4];
#pragma unroll
    for (int i = 0; i < 4; ++i)
#pragma unroll
        for (int j = 0; j < 4; ++j) acc[i][j] = (f32x4){0.f, 0.f, 0.f, 0.f};

    uint4 pa[4], pb[4];             // prefetch k-tile 0
#pragma unroll
    for (int j = 0; j < 4; ++j) {
        pa[j] = *(const uint4*)&Xb[(size_t)(m0 + sr) * D_DIM + sc + j * 8];
        pb[j] = *(const uint4*)&W [(size_t)(n0 + sr) * D_DIM + sc + j * 8];
    }

    for (int k0 = 0; k0 < D_DIM; k0 += 64) {
        __syncthreads();                       // (A) prev compute done with LDS
#pragma unroll
        for (int j = 0; j < 4; ++j) {
            *(uint4*)&As[sr][sc + j * 8] = pa[j];
            *(uint4*)&Bs[sr][sc + j * 8] = pb[j];
        }
        if (k0 + 64 < D_DIM) {                 // issue next tile under MFMA
#pragma unroll
            for (int j = 0; j < 4; ++j) {
                pa[j] = *(const uint4*)&Xb[(size_t)(m0 + sr) * D_DIM + k0 + 64 + sc + j * 8];
                pb[j] = *(const uint4*)&W [(size_t)(n0 + sr) * D_DIM + k0 + 64 + sc + j * 8];
            }
        }
        barrier_keep_vmem();                   // (B) keeps prefetch in flight

#pragma unroll
        for (int ks = 0; ks < 2; ++ks) {
            bf16x8 bfr[4];
#pragma unroll
            for (int nt = 0; nt < 4; ++nt)
                bfr[nt] = *(const bf16x8*)&Bs[wc * 64 + nt * 16 + lm][ks * 32 + lk];
#pragma unroll
            for (int mt = 0; mt < 4; ++mt) {
                bf16x8 afm = *(const bf16x8*)&As[wr * 64 + mt * 16 + lm][ks * 32 + lk];
#pragma unroll
                for (int nt = 0; nt < 4; ++nt)
                    acc[mt][nt] = MFMA16(afm, bfr[nt], acc[mt][nt]);
            }
        }
    }

    // ---- epilogue ----
    int dks[4], hs[4];
#pragma unroll
    for (int nt = 0; nt < 4; ++nt) {
        int col = n0 + wc * 64 + nt * 16 + lm;
        dks[nt] = col & 63;
        hs[nt]  = col >> 6;
    }

    if (wsel < 2) {   // Q or K: RoPE then (B,H,S,DK); Q also folds 1/sqrt(DK)
        unsigned short* Out = (wsel == 0) ? Qb : Kb;
        const float oscale = (wsel == 0) ? 0.125f : 1.0f;
        float invf[4];
#pragma unroll
        for (int nt = 0; nt < 4; ++nt)
            invf[nt] = exp2f((float)(dks[nt] >> 1) * -0.4152410119f);  // 10000^(-ip/32)
#pragma unroll
        for (int mt = 0; mt < 4; ++mt)
#pragma unroll
            for (int rg = 0; rg < 4; ++rg) {
                int m = m0 + wr * 64 + mt * 16 + ((l >> 4) << 2) + rg;
                int b = m >> 11, s = m & (S_LEN - 1);
                float pf = (float)pos[s];
#pragma unroll
                for (int nt = 0; nt < 4; ++nt) {
                    float sn, cn;
                    __sincosf(pf * invf[nt], &sn, &cn);
                    float val  = acc[mt][nt][rg];
                    float part = __shfl_xor(val, 1);   // adjacent col = RoPE partner
                    float res  = ((dks[nt] & 1) == 0) ? val * cn - part * sn
                                                      : part * sn + val * cn;
                    Out[((size_t)(b * NHEAD + hs[nt]) * S_LEN + s) * HDK + dks[nt]] =
                        f2bf(res * oscale);
                }
            }
    } else {          // V: transposed (B,H,DK,S)
#pragma unroll
        for (int mt = 0; mt < 4; ++mt)
#pragma unroll
            for (int rg = 0; rg < 4; ++rg) {
                int m = m0 + wr * 64 + mt * 16 + ((l >> 4) << 2) + rg;
                int b = m >> 11, s = m & (S_LEN - 1);
#pragma unroll
                for (int nt = 0; nt < 4; ++nt)
                    Vtb[((size_t)(b * NHEAD + hs[nt]) * HDK + dks[nt]) * S_LEN + s] =
                        f2bf(acc[mt][nt][rg]);
            }
    }
}

// ---------------------------------------------------------------------------
// Causal flash attention, bf16 MFMA, work-balanced + defer-max (T13, THR=8).
// Block = TWO 128-row q-tiles (qp, 15-qp): 34 KV iters for every block.
// 8 waves; wave w owns q-rows w*16..w*16+15.  lgkm-only barriers keep K/V
// reg-prefetch in flight.  P staged via wave-private LDS rows (dead Q tile).
// LDS: QPs 128x72 + Ks 64x72 + Vts 64x72 = 36,864 B.
// ---------------------------------------------------------------------------
__global__ __launch_bounds__(512)
void attn_kernel(const unsigned short* __restrict__ Q,
                 const unsigned short* __restrict__ K,
                 const unsigned short* __restrict__ Vt,
                 unsigned short* __restrict__ AO)
{
    __shared__ short QPs[128][72];  // phase start: Q [r][d]; loop: P [r][kcol]
    __shared__ short Ks[64][72];    // [kvrow][d]
    __shared__ short Vts[64][72];   // [d][kvrow]

    const int t  = threadIdx.x;
    const int l  = t & 63;
    const int w  = t >> 6;          // 0..7
    const int lm = l & 15;
    const int u  = l >> 4;          // 0..3
    const int lk = u * 8;
    const int qp = blockIdx.x, bh = blockIdx.y;

    const unsigned short* Qbh  = Q  + (size_t)bh * S_LEN * HDK;
    const unsigned short* Kbh  = K  + (size_t)bh * S_LEN * HDK;
    const unsigned short* Vtbh = Vt + (size_t)bh * S_LEN * HDK;

    const int r0 = t >> 3;        // 0..63
    const int ch = (t & 7) * 8;   // 0..56
    const int b  = bh >> 4, h = bh & 15;

    for (int ph = 0; ph < 2; ++ph) {
        const int qi    = ph ? (15 - qp) : qp;
        const int ktmax = 2 * qi + 1;

        uint4 q0 = *(const uint4*)&Qbh[(size_t)(qi * 128 + r0)      * HDK + ch];
        uint4 q1 = *(const uint4*)&Qbh[(size_t)(qi * 128 + r0 + 64) * HDK + ch];
        uint4 kreg = *(const uint4*)&Kbh [(size_t)r0 * HDK + ch];
        uint4 vreg = *(const uint4*)&Vtbh[(size_t)r0 * S_LEN + ch];

        barrier_keep_vmem();        // prev phase done reading QPs/Ks/Vts
        *(uint4*)&QPs[r0][ch]      = q0;
        *(uint4*)&QPs[r0 + 64][ch] = q1;
        barrier_keep_vmem();        // Q visible; kreg/vreg still in flight

        bf16x8 aq[2];               // Q A-frags (1/8 scale pre-folded)
#pragma unroll
        for (int ks = 0; ks < 2; ++ks)
            aq[ks] = *(const bf16x8*)&QPs[w * 16 + lm][ks * 32 + lk];

        f32x4 o4[4];
#pragma unroll
        for (int dt = 0; dt < 4; ++dt) o4[dt] = (f32x4){0.f, 0.f, 0.f, 0.f};
        float mrow[4] = {-__builtin_inff(), -__builtin_inff(),
                         -__builtin_inff(), -__builtin_inff()};
        float lrow[4] = {0.f, 0.f, 0.f, 0.f};

        for (int kt = 0; kt <= ktmax; ++kt) {
            barrier_keep_vmem();    // (A) prev iter's Ks/Vts/P reads done
            *(uint4*)&Ks[r0][ch]  = kreg;   // data-dep vmcnt waits cover these
            *(uint4*)&Vts[r0][ch] = vreg;
            if (kt < ktmax) {       // prefetch next tile under compute
                kreg = *(const uint4*)&Kbh [(size_t)((kt + 1) * 64 + r0) * HDK + ch];
                vreg = *(const uint4*)&Vtbh[(size_t)r0 * S_LEN + (kt + 1) * 64 + ch];
            }
            barrier_keep_vmem();    // (B)

            // S = Q K^T : wave computes 16x64
            f32x4 sacc[4];
#pragma unroll
            for (int nt = 0; nt < 4; ++nt) sacc[nt] = (f32x4){0.f, 0.f, 0.f, 0.f};
#pragma unroll
            for (int nt = 0; nt < 4; ++nt)
#pragma unroll
                for (int ks = 0; ks < 2; ++ks) {
                    bf16x8 bk = *(const bf16x8*)&Ks[nt * 16 + lm][ks * 32 + lk];
                    sacc[nt] = MFMA16(aq[ks], bk, sacc[nt]);
                }

            // ---- online softmax with deferred max (THR=8) ----
            const bool maskt = (kt * 64 + 63) > (qi * 128 + w * 16);
            float rm4[4];
#pragma unroll
            for (int rg = 0; rg < 4; ++rg) {
                if (maskt) {
                    const int row_g = qi * 128 + w * 16 + u * 4 + rg;
#pragma unroll
                    for (int nt = 0; nt < 4; ++nt)
                        if ((kt * 64 + nt * 16 + lm) > row_g)
                            sacc[nt][rg] = -__builtin_inff();
                }
                float rm = fmaxf(fmaxf(sacc[0][rg], sacc[1][rg]),
                                 fmaxf(sacc[2][rg], sacc[3][rg]));
                rm = fmaxf(rm, __shfl_xor(rm, 1));
                rm = fmaxf(rm, __shfl_xor(rm, 2));
                rm = fmaxf(rm, __shfl_xor(rm, 4));
                rm = fmaxf(rm, __shfl_xor(rm, 8));
                rm4[rg] = rm;
            }
            int need = 0;
#pragma unroll
            for (int rg = 0; rg < 4; ++rg)
                need |= (rm4[rg] > mrow[rg] + 8.0f) ? 1 : 0;
            if (__any(need)) {      // rescale pass (rare once m stabilizes)
#pragma unroll
                for (int rg = 0; rg < 4; ++rg) {
                    const float mnew = fmaxf(mrow[rg], rm4[rg]);
                    const float corr = __expf(mrow[rg] - mnew);  // exp(-inf)=0 @kt0
                    lrow[rg] *= corr;
                    mrow[rg] = mnew;
#pragma unroll
                    for (int dt = 0; dt < 4; ++dt) o4[dt][rg] *= corr;
                }
            }
#pragma unroll
            for (int rg = 0; rg < 4; ++rg) {
                float psum = 0.f;
#pragma unroll
                for (int nt = 0; nt < 4; ++nt) {
                    float p = __expf(sacc[nt][rg] - mrow[rg]);   // bounded by e^8
                    psum += p;
                    QPs[w * 16 + u * 4 + rg][nt * 16 + lm] = (short)f2bf(p);
                }
                psum += __shfl_xor(psum, 1);
                psum += __shfl_xor(psum, 2);
                psum += __shfl_xor(psum, 4);
                psum += __shfl_xor(psum, 8);
                lrow[rg] += psum;
            }

            // O += P V  (wave-private P rows; same-wave DS RAW is in-order)
#pragma unroll
            for (int ks = 0; ks < 2; ++ks) {
                bf16x8 ap = *(const bf16x8*)&QPs[w * 16 + lm][ks * 32 + lk];
#pragma unroll
                for (int dt = 0; dt < 4; ++dt) {
                    bf16x8 bv = *(const bf16x8*)&Vts[dt * 16 + lm][ks * 32 + lk];
                    o4[dt] = MFMA16(ap, bv, o4[dt]);
                }
            }
        }

        // phase epilogue: AO (B,S,D) bf16
#pragma unroll
        for (int rg = 0; rg < 4; ++rg) {
            const int row_g = qi * 128 + w * 16 + u * 4 + rg;
            const float il = 1.0f / lrow[rg];
#pragma unroll
            for (int dt = 0; dt < 4; ++dt)
                AO[((size_t)(b * S_LEN + row_g)) * D_DIM + h * HDK + dt * 16 + lm] =
                    f2bf(o4[dt][rg] * il);
        }
    }
}

// ---------------------------------------------------------------------------
// Final projection: out = AO @ Wo^T, bf16 MFMA, BK=64, fp32 out.
// ---------------------------------------------------------------------------
__global__ __launch_bounds__(256)
void proj_out_kernel(const unsigned short* __restrict__ Ab,
                     const unsigned short* __restrict__ Wob,
                     float* __restrict__ out)
{
    __shared__ short As[128][72];
    __shared__ short Bs[128][72];

    const int t  = threadIdx.x;
    const int l  = t & 63;
    const int w  = t >> 6;
    const int wr = w >> 1, wc = w & 1;
    const int lm = l & 15;
    const int lk = (l >> 4) * 8;
    const int n0 = blockIdx.x * 128;
    const int m0 = blockIdx.y * 128;
    const int sr = t >> 1;
    const int sc = (t & 1) * 32;

    f32x4 acc[4][4];
#pragma unroll
    for (int i = 0; i < 4; ++i)
#pragma unroll
        for (int j = 0; j < 4; ++j) acc[i][j] = (f32x4){0.f, 0.f, 0.f, 0.f};

    uint4 pa[4], pb[4];
#pragma unroll
    for (int j = 0; j < 4; ++j) {
        pa[j] = *(const uint4*)&Ab [(size_t)(m0 + sr) * D_DIM + sc + j * 8];
        pb[j] = *(const uint4*)&Wob[(size_t)(n0 + sr) * D_DIM + sc + j * 8];
    }

    for (int k0 = 0; k0 < D_DIM; k0 += 64) {
        __syncthreads();
#pragma unroll
        for (int j = 0; j < 4; ++j) {
            *(uint4*)&As[sr][sc + j * 8] = pa[j];
            *(uint4*)&Bs[sr][sc + j * 8] = pb[j];
        }
        if (k0 + 64 < D_DIM) {
#pragma unroll
            for (int j = 0; j < 4; ++j) {
                pa[j] = *(const uint4*)&Ab [(size_t)(m0 + sr) * D_DIM + k0 + 64 + sc + j * 8];
                pb[j] = *(const uint4*)&Wob[(size_t)(n0 + sr) * D_DIM + k0 + 64 + sc + j * 8];
            }
        }
        barrier_keep_vmem();

#pragma unroll
        for (int ks = 0; ks < 2; ++ks) {
            bf16x8 bfr[4];
#pragma unroll
            for (int nt = 0; nt < 4; ++nt)
                bfr[nt] = *(const bf16x8*)&Bs[wc * 64 + nt * 16 + lm][ks * 32 + lk];
#pragma unroll
            for (int mt = 0; mt < 4; ++mt) {
                bf16x8 afm = *(const bf16x8*)&As[wr * 64 + mt * 16 + lm][ks * 32 + lk];
#pragma unroll
                for (int nt = 0; nt < 4; ++nt)
                    acc[mt][nt] = MFMA16(afm, bfr[nt], acc[mt][nt]);
            }
        }
    }

#pragma unroll
    for (int mt = 0; mt < 4; ++mt)
#pragma unroll
        for (int rg = 0; rg < 4; ++rg) {
            int m = m0 + wr * 64 + mt * 16 + ((l >> 4) << 2) + rg;
#pragma unroll
            for (int nt = 0; nt < 4; ++nt)
                out[(size_t)m * D_DIM + n0 + wc * 64 + nt * 16 + lm] = acc[mt][nt][rg];
        }
}

// ---------------------------------------------------------------------------
extern "C" void kernel_launch(void* const* d_in, const int* in_sizes, int n_in,
                              void* d_out, int out_size, void* d_ws, size_t ws_size,
                              hipStream_t stream)
{
    const float* x   = (const float*)d_in[0];
    const float* Wq  = (const float*)d_in[1];
    const float* Wk  = (const float*)d_in[2];
    const float* Wv  = (const float*)d_in[3];
    const float* Wo  = (const float*)d_in[4];
    const int*   pos = (const int*)d_in[5];
    float* out = (float*)d_out;

    const size_t NX = NXELEM, NW = NWELEM;

    unsigned short* Xb  = (unsigned short*)d_ws;        // ws total: 88 MB
    unsigned short* Wqb = Xb  + NX;
    unsigned short* Wkb = Wqb + NW;
    unsigned short* Wvb = Wkb + NW;
    unsigned short* Wob = Wvb + NW;
    unsigned short* Qb  = Wob + NW;
    unsigned short* Kb  = Qb  + NX;
    unsigned short* Vtb = Kb  + NX;
    unsigned short* AOb = Vtb + NX;

    convert_all_kernel<<<dim3(6144), dim3(256), 0, stream>>>(x, Wq, Wk, Wv, Wo, Xb);

    proj_qkv_kernel<<<dim3(24, 64), dim3(256), 0, stream>>>(Xb, Wqb, Wkb, Wvb, pos, Qb, Kb, Vtb);

    attn_kernel<<<dim3(8, NBATCH * NHEAD), dim3(512), 0, stream>>>(Qb, Kb, Vtb, AOb);

    proj_out_kernel<<<dim3(8, 64), dim3(256), 0, stream>>>(AOb, Wob, out);
}